// Round 8
// baseline (215.829 us; speedup 1.0000x reference)
//
#include <hip/hip_runtime.h>

// YOLO loss: N=4096, S=14, B=2, NCLS=20.  Cells = 4096*14*14 = 802816.
//
// v9: persistent waves + 2-deep double-buffered pipeline, counted vmcnt.
//  - Ladder: v1/v6 (AoS direct), v5 (full coalesced staging, barriers),
//    v8 (coalesced staging, barrier-free) ALL converge at 65-67us =
//    ~2.7 TB/s logical = 17.4 lines/cy, with no pipe saturated. That is 85%
//    of the copy benchmark's implied read-line rate (~20.5 lines/cy).
//  - Untested distinction vs the copy: all our waves do issue->drain(vmcnt 0)
//    ->compute->die, exposing a full queued-latency round trip per tile and
//    dropping request pressure during compute. v9 streams: each wave owns 4
//    consecutive 64-cell tiles, double-buffers pred in LDS and tcls/tbox/mask
//    in registers, and waits with COUNTED vmcnt(16) so tile t+1's 16 load ops
//    (8 pred-DMA + 5 tcls + 1 tbox + 2 mask) stay in flight during compute(t).
//    This is the T3/T4 counted-vmcnt pattern (m218: counted-vs-drain0 was
//    +38-73% on GEMM). Exactness: mask is loaded branchlessly as BOTH a byte
//    [c] and a dword [c >> 2*mode] (both always in-bounds), so the per-iter
//    VMEM count is deterministically 16; select happens at compute time.
//  - sched_barrier(0) after each wait (rule #18). No __syncthreads (slabs are
//    wave-private). No __threadfence (v2's lesson). Atomics: 4 RMWs/wave
//    spread over 64 cache lines (v4/v6's proven fix).
//  - LDS: 2 waves x 2 bufs x 8192 B = 32 KB/block(128thr) -> 5 blocks/CU,
//    10 waves/CU. DMA overrun: 8x1024B covers 7680B tile + 512B of the next
//    tile's data inside the 8192B slab (never read); global end clamped
//    per-lane (v8-proven).
//  - Per-cell math bit-identical to v1..v8 (all passed, absmax 0).

#define NCELLS (4096 * 14 * 14)
#define NTILES (NCELLS / 64)      // 12544 tiles of 64 cells
#define TPW 4                     // tiles per wave
#define NWAVES (NTILES / TPW)     // 3136
#define NBLK (NWAVES / 2)         // 1568 blocks of 128 threads
#define NLINES 64                 // partial-sum cache lines (64 x 64B)

// ws layout (floats): lines j=0..63: ws[16j+k], k=0..3 = cls,noobj,contain,reg
// partials for waves with (wgid&63)==j.  int at float-index 1024 = mask flag.

typedef const __attribute__((address_space(1))) void* gas_t;
typedef __attribute__((address_space(3))) void* las_t;

__device__ __forceinline__ void gload_lds16(const void* g, void* l) {
    // per-lane global src; wave-uniform LDS dst (HW adds lane*16)
    __builtin_amdgcn_global_load_lds((gas_t)g, (las_t)l, 16, 0, 0);
}

__global__ void yolo_zero_kernel(float* __restrict__ ws) {
    const int t = threadIdx.x;   // 256 threads
#pragma unroll
    for (int i = 0; i < 5; ++i) {
        const int k = t + 256 * i;
        if (k < 1040) ws[k] = 0.0f;   // 64 lines + flag line
    }
}

// Detect whether the mask buffer is int32 (bytes 4k+1..4k+3 all zero) or
// 1-byte bool (random nonzero bytes at non-multiple-of-4 offsets).
__global__ void yolo_detect_kernel(const unsigned char* __restrict__ mb,
                                   int* __restrict__ flag) {
    int t = threadIdx.x;
    unsigned int found = 0;
#pragma unroll
    for (int k = 0; k < 16; ++k) {
        int slot = t * 16 + k;
        found |= mb[4 * slot + 1] | mb[4 * slot + 2] | mb[4 * slot + 3];
    }
    if (found) atomicOr(flag, 1);  // 1 => bool8 layout
}

// ---- pipeline stage helpers (static indexing only; rule #20) ----

__device__ __forceinline__ void issue_dma(const char* gpred, const char* gend,
                                          long long cellbase, char* lb,
                                          int lane) {
#pragma unroll
    for (int k = 0; k < 8; ++k) {
        const char* src = gpred + cellbase * 120 + k * 1024 + lane * 16;
        if (src + 16 > gend) src = gend - 16;  // only the grid's last lanes
        gload_lds16(src, lb + k * 1024);
    }
}

__device__ __forceinline__ void issue_regs(const float* __restrict__ tcls,
                                           const float* __restrict__ tbox,
                                           const void* __restrict__ mask,
                                           int mode, long long c,
                                           float (&tc)[20], float4& tb,
                                           unsigned int& b8, int& i32) {
    const float4* c4 = (const float4*)(tcls + 20 * c);
#pragma unroll
    for (int k = 0; k < 5; ++k) {
        float4 v = c4[k];
        tc[4 * k] = v.x;
        tc[4 * k + 1] = v.y;
        tc[4 * k + 2] = v.z;
        tc[4 * k + 3] = v.w;
    }
    tb = *(const float4*)(tbox + 4 * c);
    // branchless dual mask load: byte at [c] (in-bounds both layouts),
    // dword at [c >> 2*mode] (mode=0 int layout -> [c]; mode=1 -> clamped).
    b8 = ((const unsigned char*)mask)[c];
    i32 = ((const int*)mask)[c >> (2 * mode)];
    // NO select here: defer to compute time so no waitcnt is forced at issue.
}

__device__ __forceinline__ void tile_compute(const float* __restrict__ pcb,
                                             int lane, int mode,
                                             const float (&tc)[20], float4 tb,
                                             unsigned int b8, int i32,
                                             float& a_cls, float& a_no,
                                             float& a_cont, float& a_reg) {
    const float m = mode ? (b8 ? 1.0f : 0.0f) : (i32 ? 1.0f : 0.0f);
    const float* pc = pcb + 30 * lane;  // this cell's 30 pred floats

    // cls: m * sum((pred_cls - target_cls)^2)  (same order as v1..v8)
    float s = 0.0f;
#pragma unroll
    for (int i = 0; i < 20; ++i) {
        const float d = pc[10 + i] - tc[i];
        s += d * d;
    }
    a_cls += m * s;

    float pv[10];
#pragma unroll
    for (int i = 0; i < 10; ++i) pv[i] = pc[i];

    const float conf0 = pv[4], conf1 = pv[9];
    a_no += (1.0f - m) * (conf0 * conf0 + conf1 * conf1);

    float iou[2];
    const float at = (tb.z - tb.x) * (tb.w - tb.y);
#pragma unroll
    for (int b = 0; b < 2; ++b) {
        const int base = 5 * b;
        const float x = pv[base] / 14.0f;
        const float y = pv[base + 1] / 14.0f;
        const float w = pv[base + 2];
        const float h = pv[base + 3];
        const float p1x = x - w * 0.5f, p1y = y - h * 0.5f;
        const float p2x = x + w * 0.5f, p2y = y + h * 0.5f;
        const float ltx = fmaxf(p1x, tb.x), lty = fmaxf(p1y, tb.y);
        const float rbx = fminf(p2x, tb.z), rby = fminf(p2y, tb.w);
        const float iw = fmaxf(rbx - ltx, 0.0f), ih = fmaxf(rby - lty, 0.0f);
        const float inter = iw * ih;
        const float ap = w * h;
        iou[b] = inter / (ap + at - inter);
    }
    // jnp.argmax: first max wins -> pick box1 only if strictly greater
    const int best = (iou[1] > iou[0]) ? 5 : 0;
    const float bx = pv[best], by = pv[best + 1], bw = pv[best + 2],
                bh = pv[best + 3], bc = pv[best + 4];

    a_cont += m * (bc - 1.0f) * (bc - 1.0f);

    const float dx = bx - tb.x, dy = by - tb.y;
    const float dw = sqrtf(bw) - sqrtf(tb.z);
    const float dh = sqrtf(bh) - sqrtf(tb.w);
    a_reg += m * (dx * dx + dy * dy + dw * dw + dh * dh);
}

#define WAIT16()                                          \
    asm volatile("s_waitcnt vmcnt(16)" ::: "memory");     \
    __builtin_amdgcn_sched_barrier(0)
#define WAIT0()                                           \
    asm volatile("s_waitcnt vmcnt(0)" ::: "memory");      \
    __builtin_amdgcn_sched_barrier(0)

__global__ __launch_bounds__(128) void yolo_main_kernel(
    const float* __restrict__ pred,
    const float* __restrict__ tbox,
    const float* __restrict__ tcls,
    const void* __restrict__ mask,
    const int* __restrict__ flag,
    float* __restrict__ ws) {
    __shared__ float sp[2][2][2048];  // [wave][buf][8192 B]

    const int t = threadIdx.x;
    const int lane = t & 63;
    const int wid = t >> 6;
    const int wgid = blockIdx.x * 2 + wid;               // 0..3135
    const long long cell0 = (long long)wgid * (TPW * 64);  // wave's first cell
    const int mode = *flag;  // uniform; scalar load

    const char* const gpred = (const char*)pred;
    const char* const gend = gpred + (long long)NCELLS * 120;
    char* const lbA = (char*)&sp[wid][0][0];
    char* const lbB = (char*)&sp[wid][1][0];

    float a_cls = 0.0f, a_no = 0.0f, a_cont = 0.0f, a_reg = 0.0f;
    float tcA[20], tcB[20];
    float4 tbA, tbB;
    unsigned int b8A, b8B;
    int i32A, i32B;

    // prologue: tile 0 -> bank A
    issue_dma(gpred, gend, cell0, lbA, lane);
    issue_regs(tcls, tbox, mask, mode, cell0 + lane, tcA, tbA, b8A, i32A);

    // t=0: prefetch tile1 -> B; compute tile0 from A
    issue_dma(gpred, gend, cell0 + 64, lbB, lane);
    issue_regs(tcls, tbox, mask, mode, cell0 + 64 + lane, tcB, tbB, b8B, i32B);
    WAIT16();
    tile_compute((const float*)lbA, lane, mode, tcA, tbA, b8A, i32A,
                 a_cls, a_no, a_cont, a_reg);

    // t=1: prefetch tile2 -> A; compute tile1 from B
    issue_dma(gpred, gend, cell0 + 128, lbA, lane);
    issue_regs(tcls, tbox, mask, mode, cell0 + 128 + lane, tcA, tbA, b8A, i32A);
    WAIT16();
    tile_compute((const float*)lbB, lane, mode, tcB, tbB, b8B, i32B,
                 a_cls, a_no, a_cont, a_reg);

    // t=2: prefetch tile3 -> B; compute tile2 from A
    issue_dma(gpred, gend, cell0 + 192, lbB, lane);
    issue_regs(tcls, tbox, mask, mode, cell0 + 192 + lane, tcB, tbB, b8B, i32B);
    WAIT16();
    tile_compute((const float*)lbA, lane, mode, tcA, tbA, b8A, i32A,
                 a_cls, a_no, a_cont, a_reg);

    // t=3: compute tile3 from B (drain)
    WAIT0();
    tile_compute((const float*)lbB, lane, mode, tcB, tbB, b8B, i32B,
                 a_cls, a_no, a_cont, a_reg);

    // ---- per-wave reduction: shuffle -> 4 atomics from lane 0 ----
#pragma unroll
    for (int off = 32; off > 0; off >>= 1) {
        a_cls += __shfl_down(a_cls, off, 64);
        a_no += __shfl_down(a_no, off, 64);
        a_cont += __shfl_down(a_cont, off, 64);
        a_reg += __shfl_down(a_reg, off, 64);
    }
    if (lane == 0) {
        const int line = 16 * (wgid & (NLINES - 1));
        atomicAdd(&ws[line + 0], a_cls);
        atomicAdd(&ws[line + 1], a_no);
        atomicAdd(&ws[line + 2], a_cont);
        atomicAdd(&ws[line + 3], a_reg);
    }
}

__global__ void yolo_final_kernel(const float* __restrict__ ws,
                                  float* __restrict__ out) {
    const int t = threadIdx.x;   // 64 threads, one partial line each
    float4 v = ((const float4*)ws)[4 * t];   // line t: ws[16t .. 16t+3]
#pragma unroll
    for (int off = 32; off > 0; off >>= 1) {
        v.x += __shfl_down(v.x, off, 64);
        v.y += __shfl_down(v.y, off, 64);
        v.z += __shfl_down(v.z, off, 64);
        v.w += __shfl_down(v.w, off, 64);
    }
    if (t == 0) {
        const float inv_n = 1.0f / 4096.0f;
        const float cls = v.x * inv_n;
        const float noobj = v.y * inv_n;
        const float contain = v.z * inv_n;
        const float reg = v.w * inv_n;
        out[0] = cls + 0.5f * noobj + 5.0f * reg + contain;
        out[1] = reg;
        out[2] = contain;
        out[3] = noobj;
        out[4] = cls;
    }
}

extern "C" void kernel_launch(void* const* d_in, const int* in_sizes, int n_in,
                              void* d_out, int out_size, void* d_ws,
                              size_t ws_size, hipStream_t stream) {
    const float* pred = (const float*)d_in[0];
    const float* tbox = (const float*)d_in[1];
    const float* tcls = (const float*)d_in[2];
    const void* mask = d_in[3];
    float* ws = (float*)d_ws;
    float* out = (float*)d_out;

    yolo_zero_kernel<<<1, 256, 0, stream>>>(ws);
    yolo_detect_kernel<<<1, 256, 0, stream>>>((const unsigned char*)mask,
                                              (int*)(ws + 1024));
    yolo_main_kernel<<<NBLK, 128, 0, stream>>>(pred, tbox, tcls, mask,
                                               (const int*)(ws + 1024), ws);
    yolo_final_kernel<<<1, 64, 0, stream>>>(ws, out);
}